// Round 11
// baseline (109.087 us; speedup 1.0000x reference)
//
#include <hip/hip_runtime.h>

#define B_   8
#define K_   256
#define C_   8
#define PS   64
#define H_   512
#define W_   512
#define TH   32
#define TW   32

// Detect whether coords buffer is int64 (little-endian lo/hi pairs, hi==0 since
// coords are small non-negative) or already int32; write decoded int32 coords.
__global__ void decode_coords_kernel(const int* __restrict__ raw,
                                     int* __restrict__ coords, int n) {
    __shared__ int s_nonzero;
    if (threadIdx.x == 0) s_nonzero = 0;
    __syncthreads();
    int local = 0;
    for (int i = 2 * threadIdx.x + 1; i < n; i += 2 * blockDim.x) {
        if (raw[i] != 0) local = 1;
    }
    if (local) atomicOr(&s_nonzero, 1);
    __syncthreads();
    bool is64 = (s_nonzero == 0);  // all odd words zero -> int64 layout
    for (int i = threadIdx.x; i < n; i += blockDim.x) {
        coords[i] = is64 ? raw[2 * i] : raw[i];
    }
}

// One block per (32x32 tile, channel-pair); thread owns (1 row, 4 consecutive x).
// Per patch per thread: 4x global_load_dwordx4 (two adjacent quads x 2 channels)
// instead of 8 scalar loads — 16B/lane contiguous (fill-kernel-class coalescing;
// R2-R10 all plateaued at ~3.4 TB/s on 4B scattered loads = request-rate cap).
// Patch misalignment d=(x0-c)&3 is WAVE-UNIFORM (c readfirstlane'd) -> uniform
// 4-way switch gives fully static component selection. Quad addresses clamped
// to [pxlo&~3, pxhi&~3]: provably within already-fetched 64B lines (no R3
// over-fetch) and within the 64-float row (no R6 OOB). Masks use unclamped
// coords. No LDS accumulator, no atomics.
__global__ __launch_bounds__(256)
void gather_kernel(const float* __restrict__ logits,
                   const int* __restrict__ coords,
                   float* __restrict__ out) {
    const int b   = blockIdx.z >> 2;
    const int cp  = blockIdx.z & 3;    // channels {2cp, 2cp+1}
    const int ty0 = blockIdx.y * TH;
    const int tx0 = blockIdx.x * TW;
    const int tid = threadIdx.x;

    __shared__ int s_rc[K_];    // packed (r<<16)|c, compacted in k-order
    __shared__ int s_kk[K_];    // accepted patch index
    __shared__ unsigned long long s_mask[4];

    // --- Phase 1: ordered accept-list compaction (one coord per thread) ---
    {
        int2 cc = ((const int2*)coords)[b * K_ + tid];
        bool hit = (cc.x < ty0 + TH) && (cc.x + PS > ty0) &&
                   (cc.y < tx0 + TW) && (cc.y + PS > tx0);
        unsigned long long m = __ballot(hit);
        const int wid = tid >> 6, lane = tid & 63;
        if (lane == 0) s_mask[wid] = m;
        __syncthreads();
        int base = 0;
        for (int w = 0; w < wid; ++w) base += __popcll(s_mask[w]);
        if (hit) {
            int pos = base + __popcll(m & ((1ull << lane) - 1ull));
            s_rc[pos] = (cc.x << 16) | cc.y;
            s_kk[pos] = tid;
        }
    }
    int nacc = 0;
    for (int w = 0; w < 4; ++w) nacc += __popcll(s_mask[w]);
    __syncthreads();

    // --- Phase 2: float4 gather, 2 channels, 4 px per thread ---
    const int x0 = tx0 + ((tid & 7) << 2);   // owned quad start (4-aligned)
    const int y  = ty0 + (tid >> 3);         // owned row

    float acc0[4], acc1[4], cnt[4];
#pragma unroll
    for (int i = 0; i < 4; ++i) { acc0[i] = acc1[i] = cnt[i] = 0.0f; }

#define COMP(V, J) ((J) == 0 ? (V).x : (J) == 1 ? (V).y : (J) == 2 ? (V).z : (V).w)
#define SEL1(D, I)                                                          \
    {                                                                       \
        const float v0_ = ((D) + (I) < 4) ? COMP(A0, (D) + (I))             \
                                          : COMP(B0, (D) + (I) - 4);        \
        const float v1_ = ((D) + (I) < 4) ? COMP(A1, (D) + (I))             \
                                          : COMP(B1, (D) + (I) - 4);        \
        acc0[(I)] = fmaf(v0_, f[(I)], acc0[(I)]);                           \
        acc1[(I)] = fmaf(v1_, f[(I)], acc1[(I)]);                           \
    }
#define SEL(D) SEL1(D, 0) SEL1(D, 1) SEL1(D, 2) SEL1(D, 3)

    for (int t = 0; t < nacc; ++t) {
        const int rcp = __builtin_amdgcn_readfirstlane(s_rc[t]);
        const int kk  = __builtin_amdgcn_readfirstlane(s_kk[t]);
        const int r = rcp >> 16, c = rcp & 0xffff;
        const float* __restrict__ pbase =
            logits + (((size_t)(b * K_ + kk)) << 15) + ((size_t)(2 * cp) << 12);

        // Overlap window in patch coords (non-empty by construction).
        const int pxlo = max(0, tx0 - c);
        const int pxhi = min(PS - 1, tx0 + TW - 1 - c);
        const int pylo = max(0, ty0 - r);
        const int pyhi = min(PS - 1, ty0 + TH - 1 - r);

        const int py    = y - r;
        const int pyc   = min(max(py, pylo), pyhi);
        const bool rowok = (py == pyc);
        const int rowoff = pyc << 6;

        const int px0 = x0 - c;          // in [-31, 91]
        const int qv  = px0 & ~3;        // virtual aligned quad (may be OOW)
        const int d   = px0 & 3;         // WAVE-UNIFORM (c uniform, x0 = 0 mod 4)
        const int lo4 = pxlo & ~3, hi4 = pxhi & ~3;
        const int aA  = min(max(qv, lo4), hi4);       // clamped in-window quads
        const int aB  = min(max(qv + 4, lo4), hi4);   // (valid comps unaffected)

        const float4 A0 = *(const float4*)(pbase + rowoff + aA);
        const float4 B0 = *(const float4*)(pbase + rowoff + aB);
        const float4 A1 = *(const float4*)(pbase + 4096 + rowoff + aA);
        const float4 B1 = *(const float4*)(pbase + 4096 + rowoff + aB);

        float f[4];
#pragma unroll
        for (int i = 0; i < 4; ++i) {
            const int px = px0 + i;
            f[i] = (rowok && px >= pxlo && px <= pxhi) ? 1.0f : 0.0f;
            cnt[i] += f[i];
        }

        switch (__builtin_amdgcn_readfirstlane(d)) {
            case 0:  { SEL(0) } break;
            case 1:  { SEL(1) } break;
            case 2:  { SEL(2) } break;
            default: { SEL(3) } break;
        }
    }

    // --- Phase 3: fused finalize + float4 store (written exactly once) ---
    float4 o0, o1;
    float* po0 = (float*)&o0;
    float* po1 = (float*)&o1;
#pragma unroll
    for (int i = 0; i < 4; ++i) {
        const bool covered = cnt[i] > 1e-6f;
        const float inv = 1.0f / fmaxf(cnt[i], 1e-6f);
        po0[i] = covered ? acc0[i] * inv : -10.0f;
        po1[i] = covered ? acc1[i] * inv : -10.0f;
    }
    const size_t base0 = (((size_t)(b * C_ + 2 * cp)) << 18) + y * W_ + x0;
    *(float4*)(out + base0)               = o0;
    *(float4*)(out + base0 + (1ull << 18)) = o1;
}

extern "C" void kernel_launch(void* const* d_in, const int* in_sizes, int n_in,
                              void* d_out, int out_size, void* d_ws, size_t ws_size,
                              hipStream_t stream) {
    const float* logits = (const float*)d_in[0];
    const int* raw_coords = (const int*)d_in[1];
    float* out = (float*)d_out;

    int* coords = (int*)d_ws;  // 16 KiB decoded coords

    decode_coords_kernel<<<1, 256, 0, stream>>>(raw_coords, coords, B_ * K_ * 2);

    dim3 grid(W_ / TW, H_ / TH, B_ * 4);  // 16 x 16 x 32 = 8192 blocks
    gather_kernel<<<grid, 256, 0, stream>>>(logits, coords, out);
}

// Round 12
// 75.745 us; speedup vs baseline: 1.4402x; 1.4402x over previous
//
#include <hip/hip_runtime.h>

#define B_   8
#define K_   256
#define C_   8
#define PS   64
#define H_   512
#define W_   512
#define TH   32
#define TW   32

// Detect whether coords buffer is int64 (little-endian lo/hi pairs, hi==0 since
// coords are small non-negative) or already int32; write decoded int32 coords.
__global__ void decode_coords_kernel(const int* __restrict__ raw,
                                     int* __restrict__ coords, int n) {
    __shared__ int s_nonzero;
    if (threadIdx.x == 0) s_nonzero = 0;
    __syncthreads();
    int local = 0;
    for (int i = 2 * threadIdx.x + 1; i < n; i += 2 * blockDim.x) {
        if (raw[i] != 0) local = 1;
    }
    if (local) atomicOr(&s_nonzero, 1);
    __syncthreads();
    bool is64 = (s_nonzero == 0);  // all odd words zero -> int64 layout
    for (int i = threadIdx.x; i < n; i += blockDim.x) {
        coords[i] = is64 ? raw[2 * i] : raw[i];
    }
}

// R10 body (best measured: 100.6us) + XCD-LOCALITY SWIZZLE.
// Work unit w = ((b*16+ty)*16+tx)*4 + cp. Sharers of the same patch lines
// (4 cp-blocks of one tile, horizontally neighboring tiles) are CONSECUTIVE
// in w. Hardware round-robins linear wgid across 8 XCDs, so launch 1D and
// invert: w = (wgid%8)*1024 + wgid/8  (bijective, 8192%8==0). Consecutive w
// -> same XCD, adjacent in time -> patch lines fetched once into that XCD's
// L2 and re-consumed at L2 latency instead of L3/HBM (the R2-R11 ~100us
// plateau = MSHR-cap x ~600cy average latency; occupancy can't fix it,
// latency reduction can).
__global__ __launch_bounds__(256)
void gather_kernel(const float* __restrict__ logits,
                   const int* __restrict__ coords,
                   float* __restrict__ out) {
    const int wgid = blockIdx.x;
    const int w    = (wgid & 7) * 1024 + (wgid >> 3);  // XCD-contiguous work id
    const int cp   = w & 3;            // channels {2cp, 2cp+1}
    const int tile = w >> 2;
    const int tx   = tile & 15;
    const int ty   = (tile >> 4) & 15;
    const int b    = tile >> 8;

    const int ty0 = ty * TH;
    const int tx0 = tx * TW;
    const int tid = threadIdx.x;

    __shared__ int s_rc[K_];    // packed (r<<16)|c, compacted in k-order
    __shared__ int s_kk[K_];    // accepted patch index
    __shared__ unsigned long long s_mask[4];

    // --- Phase 1: ordered accept-list compaction (one coord per thread) ---
    {
        int2 cc = ((const int2*)coords)[b * K_ + tid];
        bool hit = (cc.x < ty0 + TH) && (cc.x + PS > ty0) &&
                   (cc.y < tx0 + TW) && (cc.y + PS > tx0);
        unsigned long long m = __ballot(hit);
        const int wid = tid >> 6, lane = tid & 63;
        if (lane == 0) s_mask[wid] = m;
        __syncthreads();
        int base = 0;
        for (int w2 = 0; w2 < wid; ++w2) base += __popcll(s_mask[w2]);
        if (hit) {
            int pos = base + __popcll(m & ((1ull << lane) - 1ull));
            s_rc[pos] = (cc.x << 16) | cc.y;
            s_kk[pos] = tid;
        }
    }
    int nacc = 0;
    for (int w2 = 0; w2 < 4; ++w2) nacc += __popcll(s_mask[w2]);
    __syncthreads();

    // --- Phase 2: register-accumulate gather, 2 channels ---
    float acc0[4], acc1[4], cnt[4];
#pragma unroll
    for (int j = 0; j < 4; ++j) { acc0[j] = acc1[j] = cnt[j] = 0.0f; }

    const int x  = tx0 + (tid & 31);   // owned column
    const int y0 = ty0 + (tid >> 5);   // owned rows: y0 + {0,8,16,24}

#pragma unroll 2
    for (int t = 0; t < nacc; ++t) {
        const int rcp = __builtin_amdgcn_readfirstlane(s_rc[t]);
        const int kk  = __builtin_amdgcn_readfirstlane(s_kk[t]);
        const int r = rcp >> 16, c = rcp & 0xffff;
        const float* __restrict__ pbase =
            logits + (((size_t)(b * K_ + kk)) << 15) + ((size_t)(2 * cp) << 12);

        // Valid overlap window in patch coords (non-empty by construction).
        const int pxlo = max(0, tx0 - c);
        const int pxhi = min(PS - 1, tx0 + TW - 1 - c);
        const int pylo = max(0, ty0 - r);
        const int pyhi = min(PS - 1, ty0 + TH - 1 - r);

        const int  px  = x - c;
        const int  pxc = min(max(px, pxlo), pxhi);   // in-window (in-bounds)
        const bool okx = (px == pxc);

        float f[4];
        int   off[4];
#pragma unroll
        for (int j = 0; j < 4; ++j) {
            const int py  = y0 + j * 8 - r;
            const int pyc = min(max(py, pylo), pyhi);
            f[j]   = (okx && (py == pyc)) ? 1.0f : 0.0f;
            off[j] = (pyc << 6) + pxc;               // inside window, fetched anyway
        }

        float v0[4], v1[4];
#pragma unroll
        for (int j = 0; j < 4; ++j) v0[j] = pbase[off[j]];
#pragma unroll
        for (int j = 0; j < 4; ++j) v1[j] = pbase[4096 + off[j]];

#pragma unroll
        for (int j = 0; j < 4; ++j) {
            cnt[j] += f[j];
            acc0[j] = fmaf(v0[j], f[j], acc0[j]);
            acc1[j] = fmaf(v1[j], f[j], acc1[j]);
        }
    }

    // --- Phase 3: fused finalize + store (2 channels, written exactly once) ---
#pragma unroll
    for (int j = 0; j < 4; ++j) {
        const int y = y0 + j * 8;
        const bool covered = cnt[j] > 1e-6f;
        const float inv = 1.0f / fmaxf(cnt[j], 1e-6f);
        const size_t o0 = (((size_t)(b * C_ + 2 * cp)) << 18) + y * W_ + x;
        out[o0]                 = covered ? acc0[j] * inv : -10.0f;
        out[o0 + (1ull << 18)]  = covered ? acc1[j] * inv : -10.0f;
    }
}

extern "C" void kernel_launch(void* const* d_in, const int* in_sizes, int n_in,
                              void* d_out, int out_size, void* d_ws, size_t ws_size,
                              hipStream_t stream) {
    const float* logits = (const float*)d_in[0];
    const int* raw_coords = (const int*)d_in[1];
    float* out = (float*)d_out;

    int* coords = (int*)d_ws;  // 16 KiB decoded coords

    decode_coords_kernel<<<1, 256, 0, stream>>>(raw_coords, coords, B_ * K_ * 2);

    gather_kernel<<<8192, 256, 0, stream>>>(logits, coords, out);
}

// Round 13
// 65.457 us; speedup vs baseline: 1.6665x; 1.1572x over previous
//
#include <hip/hip_runtime.h>

#define B_   8
#define K_   256
#define C_   8
#define PS   64
#define H_   512
#define W_   512
#define TH   32
#define TW   32

// Detect whether coords buffer is int64 (little-endian lo/hi pairs, hi==0 since
// coords are small non-negative) or already int32; write decoded int32 coords.
__global__ void decode_coords_kernel(const int* __restrict__ raw,
                                     int* __restrict__ coords, int n) {
    __shared__ int s_nonzero;
    if (threadIdx.x == 0) s_nonzero = 0;
    __syncthreads();
    int local = 0;
    for (int i = 2 * threadIdx.x + 1; i < n; i += 2 * blockDim.x) {
        if (raw[i] != 0) local = 1;
    }
    if (local) atomicOr(&s_nonzero, 1);
    __syncthreads();
    bool is64 = (s_nonzero == 0);  // all odd words zero -> int64 layout
    for (int i = threadIdx.x; i < n; i += blockDim.x) {
        coords[i] = is64 ? raw[2 * i] : raw[i];
    }
}

// R12 (75.7us) + two locality refinements:
//  (1) Work order within an XCD: w = ((b*4+cp)*16+ty)*16+tx, tx INNERMOST.
//      Each XCD still owns one full batch (w partition unchanged), but
//      consecutive blocks now sweep ONE channel plane across a tile row —
//      patch-boundary cachelines shared by horizontally adjacent tiles are
//      L2-hot, and accesses stay within the same DRAM pages. (R12 had cp
//      fastest: adjacent blocks read planes 16KB apart, sharers 4 slots away.)
//  (2) Output written with __builtin_nontemporal_store: the 64MB write stream
//      (8MB/XCD, 2x L2 capacity) no longer evicts patch lines between their
//      first and second consumer.
__global__ __launch_bounds__(256)
void gather_kernel(const float* __restrict__ logits,
                   const int* __restrict__ coords,
                   float* __restrict__ out) {
    const int wgid = blockIdx.x;
    const int w    = (wgid & 7) * 1024 + (wgid >> 3);  // XCD-contiguous work id
    const int tx   = w & 15;
    const int ty   = (w >> 4) & 15;
    const int cp   = (w >> 8) & 3;     // channels {2cp, 2cp+1}
    const int b    = w >> 10;

    const int ty0 = ty * TH;
    const int tx0 = tx * TW;
    const int tid = threadIdx.x;

    __shared__ int s_rc[K_];    // packed (r<<16)|c, compacted in k-order
    __shared__ int s_kk[K_];    // accepted patch index
    __shared__ unsigned long long s_mask[4];

    // --- Phase 1: ordered accept-list compaction (one coord per thread) ---
    {
        int2 cc = ((const int2*)coords)[b * K_ + tid];
        bool hit = (cc.x < ty0 + TH) && (cc.x + PS > ty0) &&
                   (cc.y < tx0 + TW) && (cc.y + PS > tx0);
        unsigned long long m = __ballot(hit);
        const int wid = tid >> 6, lane = tid & 63;
        if (lane == 0) s_mask[wid] = m;
        __syncthreads();
        int base = 0;
        for (int w2 = 0; w2 < wid; ++w2) base += __popcll(s_mask[w2]);
        if (hit) {
            int pos = base + __popcll(m & ((1ull << lane) - 1ull));
            s_rc[pos] = (cc.x << 16) | cc.y;
            s_kk[pos] = tid;
        }
    }
    int nacc = 0;
    for (int w2 = 0; w2 < 4; ++w2) nacc += __popcll(s_mask[w2]);
    __syncthreads();

    // --- Phase 2: register-accumulate gather, 2 channels ---
    float acc0[4], acc1[4], cnt[4];
#pragma unroll
    for (int j = 0; j < 4; ++j) { acc0[j] = acc1[j] = cnt[j] = 0.0f; }

    const int x  = tx0 + (tid & 31);   // owned column
    const int y0 = ty0 + (tid >> 5);   // owned rows: y0 + {0,8,16,24}

#pragma unroll 2
    for (int t = 0; t < nacc; ++t) {
        const int rcp = __builtin_amdgcn_readfirstlane(s_rc[t]);
        const int kk  = __builtin_amdgcn_readfirstlane(s_kk[t]);
        const int r = rcp >> 16, c = rcp & 0xffff;
        const float* __restrict__ pbase =
            logits + (((size_t)(b * K_ + kk)) << 15) + ((size_t)(2 * cp) << 12);

        // Valid overlap window in patch coords (non-empty by construction).
        const int pxlo = max(0, tx0 - c);
        const int pxhi = min(PS - 1, tx0 + TW - 1 - c);
        const int pylo = max(0, ty0 - r);
        const int pyhi = min(PS - 1, ty0 + TH - 1 - r);

        const int  px  = x - c;
        const int  pxc = min(max(px, pxlo), pxhi);   // in-window (in-bounds)
        const bool okx = (px == pxc);

        float f[4];
        int   off[4];
#pragma unroll
        for (int j = 0; j < 4; ++j) {
            const int py  = y0 + j * 8 - r;
            const int pyc = min(max(py, pylo), pyhi);
            f[j]   = (okx && (py == pyc)) ? 1.0f : 0.0f;
            off[j] = (pyc << 6) + pxc;               // inside window, fetched anyway
        }

        float v0[4], v1[4];
#pragma unroll
        for (int j = 0; j < 4; ++j) v0[j] = pbase[off[j]];
#pragma unroll
        for (int j = 0; j < 4; ++j) v1[j] = pbase[4096 + off[j]];

#pragma unroll
        for (int j = 0; j < 4; ++j) {
            cnt[j] += f[j];
            acc0[j] = fmaf(v0[j], f[j], acc0[j]);
            acc1[j] = fmaf(v1[j], f[j], acc1[j]);
        }
    }

    // --- Phase 3: fused finalize + nontemporal store (written exactly once) ---
#pragma unroll
    for (int j = 0; j < 4; ++j) {
        const int y = y0 + j * 8;
        const bool covered = cnt[j] > 1e-6f;
        const float inv = 1.0f / fmaxf(cnt[j], 1e-6f);
        const size_t o0 = (((size_t)(b * C_ + 2 * cp)) << 18) + y * W_ + x;
        __builtin_nontemporal_store(covered ? acc0[j] * inv : -10.0f, out + o0);
        __builtin_nontemporal_store(covered ? acc1[j] * inv : -10.0f,
                                    out + o0 + (1ull << 18));
    }
}

extern "C" void kernel_launch(void* const* d_in, const int* in_sizes, int n_in,
                              void* d_out, int out_size, void* d_ws, size_t ws_size,
                              hipStream_t stream) {
    const float* logits = (const float*)d_in[0];
    const int* raw_coords = (const int*)d_in[1];
    float* out = (float*)d_out;

    int* coords = (int*)d_ws;  // 16 KiB decoded coords

    decode_coords_kernel<<<1, 256, 0, stream>>>(raw_coords, coords, B_ * K_ * 2);

    gather_kernel<<<8192, 256, 0, stream>>>(logits, coords, out);
}